// Round 18
// baseline (207.808 us; speedup 1.0000x reference)
//
#include <hip/hip_runtime.h>

#define NN 50000
#define NE 1600000
#define BSTRIDE 96   // max degree slots; Poisson(32) tail at 96 is ~e^-41 per node
#define C_BKT 196    // dst buckets of 256 nodes: ceil(50000/256)
#define P1_BLKS 512
#define P1_CHUNK 3125 // NE / P1_BLKS exactly
#define CAP 56       // per-(block,bucket) cell capacity; Poisson(16) P(>=56) ~ 1e-14
#define XCVT_BLKS 1563   // ceil(1600000 float4 / 1024)
#define WCVT_BLKS 48     // 49152 / 1024 exactly
#define PP_PREP (XCVT_BLKS + WCVT_BLKS)
#define RGRP 3128    // padded 16-row groups (50048 rows) for packed A arrays

typedef __bf16 bf16x8 __attribute__((ext_vector_type(8)));
typedef float  f32x4  __attribute__((ext_vector_type(4)));
typedef float  f32x2  __attribute__((ext_vector_type(2)));

// ---------- bf16 helpers (RNE) ----------
__device__ __forceinline__ float bfLo(uint u) { union { uint i; float f; } v; v.i = u << 16; return v.f; }
__device__ __forceinline__ float bfHi(uint u) { union { uint i; float f; } v; v.i = u & 0xffff0000u; return v.f; }
__device__ __forceinline__ ushort f2bf(float f) {
    union { float f; uint i; } v; v.f = f;
    uint r = v.i + 0x7fffu + ((v.i >> 16) & 1u);
    return (ushort)(r >> 16);
}
__device__ __forceinline__ uint pack2(float a, float b) {
    return (uint)f2bf(a) | ((uint)f2bf(b) << 16);
}
__device__ __forceinline__ bf16x8 load8(const ushort* p) {
    union { uint4 u; bf16x8 b; } v; v.u = *(const uint4*)p; return v.b;
}

#define ACC8(u) { a0 += bfLo(u.x); a1 += bfHi(u.x); a2 += bfLo(u.y); a3 += bfHi(u.y); \
                  a4 += bfLo(u.z); a5 += bfHi(u.z); a6 += bfLo(u.w); a7 += bfHi(u.w); }

// fp8 x4 (one uint) -> 4 fp32 accumulated at offset o
#define CVA(u, o) { f32x2 p0 = __builtin_amdgcn_cvt_pk_f32_fp8((int)(u), 0); \
                    f32x2 p1 = __builtin_amdgcn_cvt_pk_f32_fp8((int)(u), 1); \
                    a[(o)+0] += p0.x; a[(o)+1] += p0.y; a[(o)+2] += p1.x; a[(o)+3] += p1.y; }
#define ACCF8(v) { CVA((v).x, 0); CVA((v).y, 4); CVA((v).z, 8); CVA((v).w, 12); }

// MFMA-fragment-packed offset (ushort units) for element (row/col n, depth k):
// tile = (n>>4)*4 + (k>>5); within-tile: quad=(k>>3)&3, m=n&15, j=k&7
// off = tile*512 + quad*128 + m*8 + j  -> one wave tile = contiguous 1 KB.
__device__ __forceinline__ int pkOff(int n, int k) {
    return (((n >> 4) * 4 + (k >> 5)) * 512) + (((k >> 3) & 3) * 128) + ((n & 15) * 8) + (k & 7);
}

// ---------- fused prep (x->packed bf16 + x->fp8, weights->packed bf16) + radix pass 1 ----------
__global__ __launch_bounds__(1024) void k_pp(
    const float4* __restrict__ x, ushort* __restrict__ xbp, uint* __restrict__ xf8,
    const float* __restrict__ W1l, const float* __restrict__ W1r,
    const float* __restrict__ W2l, const float* __restrict__ W2r,
    ushort* __restrict__ T1l, ushort* __restrict__ T1r,
    ushort* __restrict__ T2l, ushort* __restrict__ T2r,
    const int* __restrict__ src, const int* __restrict__ dst,
    uint* __restrict__ cells, ushort* __restrict__ cnt) {
    __shared__ uint hist[C_BKT];
    const int b = blockIdx.x;
    const int tid = threadIdx.x;
    if (b < XCVT_BLKS) {
        int i = b * 1024 + tid;                   // 1.6M float4 total
        if (i < NN * 128 / 4) {
            float4 v = x[i];
            int r = i >> 5, k0 = (i & 31) * 4;    // row, depth base (4 consecutive k)
            ushort4 o; o.x = f2bf(v.x); o.y = f2bf(v.y); o.z = f2bf(v.z); o.w = f2bf(v.w);
            *(ushort4*)(xbp + pkOff(r, k0)) = o;  // packed write (8-B aligned)
            uint rr = (uint)__builtin_amdgcn_cvt_pk_fp8_f32(v.x, v.y, 0, 0);
            rr = (uint)__builtin_amdgcn_cvt_pk_fp8_f32(v.z, v.w, (int)rr, 1);
            xf8[i] = rr;                          // 4 fp8 = dims 4i..4i+3, row-major
        }
    } else if (b < PP_PREP) {
        int i = (b - XCVT_BLKS) * 1024 + tid;     // 0 .. 49151
        if (i < 16384) {
            int k = i >> 7, n = i & 127; T1l[pkOff(n, k)] = f2bf(W1l[i]);
        } else if (i < 32768) {
            int j = i - 16384; int k = j >> 7, n = j & 127; T1r[pkOff(n, k)] = f2bf(W1r[j]);
        } else if (i < 40960) {
            int j = i - 32768; int k = j >> 6, n = j & 63;  T2l[pkOff(n, k)] = f2bf(W2l[j]);
        } else {
            int j = i - 40960; int k = j >> 6, n = j & 63;  T2r[pkOff(n, k)] = f2bf(W2r[j]);
        }
    } else {
        // radix pass 1: partition edges into block-private (bucket) cells, LDS atomics only
        const int b2 = b - PP_PREP;               // 0..511
        for (int i = tid; i < C_BKT; i += 1024) hist[i] = 0;
        __syncthreads();
        const int beg = b2 * P1_CHUNK;
        uint* myCells = cells + (size_t)b2 * C_BKT * CAP;
        for (int i = beg + tid; i < beg + P1_CHUNK; i += 1024) {
            int d = dst[i];
            int s = src[i];
            int c = d >> 8;
            uint p = atomicAdd(&hist[c], 1);
            if (p < CAP) myCells[c * CAP + p] = ((uint)(d & 255) << 16) | (uint)s;
        }
        __syncthreads();
        for (int i = tid; i < C_BKT; i += 1024)
            cnt[(size_t)b2 * C_BKT + i] = (ushort)min(hist[i], (uint)CAP);
    }
}

// ---------- radix pass 2: per-bucket gather, final col slots via LDS atomics ----------
__global__ __launch_bounds__(1024) void k_part2(const uint* __restrict__ cells,
                        const ushort* __restrict__ cnt,
                        ushort* __restrict__ col, int* __restrict__ deg) {
    __shared__ uint hist[256];
    const int c = blockIdx.x;
    if (threadIdx.x < 256) hist[threadIdx.x] = 0;
    __syncthreads();
    const int b = threadIdx.x >> 1;            // 0..511
    const int sub = threadIdx.x & 1;
    const uint* cell = cells + ((size_t)b * C_BKT + c) * CAP;
    const int n = cnt[(size_t)b * C_BKT + c];
    const int nodeBase = c << 8;
    for (int j = sub; j < n; j += 2) {
        uint e = cell[j];
        int dl = e >> 16;
        uint p = atomicAdd(&hist[dl], 1);
        if (p < BSTRIDE)
            col[(size_t)(nodeBase + dl) * BSTRIDE + p] = (ushort)(e & 0xFFFF);
    }
    __syncthreads();
    if (threadIdx.x < 256) {
        int node = nodeBase + threadIdx.x;
        if (node < NN) deg[node] = (int)hist[threadIdx.x];
    }
}

// ---------- aggregation, 128-dim fp8 rows -> PACKED bf16 agg1 ----------
// one wave per node; 8 lanes x 16B cover one 128B row. 4 gathers in flight:
// the 32-neighbor main step covers the mean-degree node in ONE iteration.
__global__ void k_agg128(const uchar* __restrict__ xf8, const ushort* __restrict__ col,
                         const int* __restrict__ deg, ushort* __restrict__ aggp) {
    int node = (blockIdx.x * blockDim.x + threadIdx.x) >> 6;
    int lane = threadIdx.x & 63;
    int q = lane >> 3;         // neighbor slot within group of 8
    int c = lane & 7;          // dim group: dims c*16 .. c*16+15
    int d = deg[node];
    int dd = min(d, BSTRIDE);
    const ushort* cb = col + (size_t)node * BSTRIDE;
    float a[16];
    #pragma unroll
    for (int i = 0; i < 16; i++) a[i] = 0.f;
    for (int j0 = 0; j0 < dd; j0 += 64) {
        int idx = (j0 + lane < dd) ? (int)cb[j0 + lane] : 0;
        int cnt = min(64, dd - j0);
        int t = 0;
        for (; t + 32 <= cnt; t += 32) {     // 32 neighbors, 4 loads in flight
            int s0 = __shfl(idx, t + q);
            int s1 = __shfl(idx, t + 8 + q);
            int s2 = __shfl(idx, t + 16 + q);
            int s3 = __shfl(idx, t + 24 + q);
            uint4 u0 = *(const uint4*)(xf8 + (size_t)s0 * 128 + c * 16);
            uint4 u1 = *(const uint4*)(xf8 + (size_t)s1 * 128 + c * 16);
            uint4 u2 = *(const uint4*)(xf8 + (size_t)s2 * 128 + c * 16);
            uint4 u3 = *(const uint4*)(xf8 + (size_t)s3 * 128 + c * 16);
            ACCF8(u0); ACCF8(u1); ACCF8(u2); ACCF8(u3);
        }
        for (; t + 16 <= cnt; t += 16) {     // 16 neighbors, 2 loads in flight
            int s0 = __shfl(idx, t + q);
            int s1 = __shfl(idx, t + 8 + q);
            uint4 u0 = *(const uint4*)(xf8 + (size_t)s0 * 128 + c * 16);
            uint4 u1 = *(const uint4*)(xf8 + (size_t)s1 * 128 + c * 16);
            ACCF8(u0); ACCF8(u1);
        }
        for (; t < cnt; t += 8) {
            int s = __shfl(idx, t + q);
            if (t + q < cnt) {
                uint4 u = *(const uint4*)(xf8 + (size_t)s * 128 + c * 16);
                ACCF8(u);
            }
        }
    }
    #pragma unroll
    for (int m = 8; m < 64; m <<= 1) {
        #pragma unroll
        for (int i = 0; i < 16; i++) a[i] += __shfl_xor(a[i], m);
    }
    if (q == 0) {
        float inv = 1.f / fmaxf((float)d, 1.f);
        // packed write: dims c*16..+7 -> (kt=c>>1, quad=(c&1)*2), dims +8..+15 -> quad+1
        int base = ((node >> 4) * 4 + (c >> 1)) * 512 + ((c & 1) * 2) * 128 + (node & 15) * 8;
        uint4 o;
        o.x = pack2(a[0] * inv, a[1] * inv);
        o.y = pack2(a[2] * inv, a[3] * inv);
        o.z = pack2(a[4] * inv, a[5] * inv);
        o.w = pack2(a[6] * inv, a[7] * inv);
        *(uint4*)(aggp + base) = o;
        o.x = pack2(a[8] * inv, a[9] * inv);
        o.y = pack2(a[10] * inv, a[11] * inv);
        o.z = pack2(a[12] * inv, a[13] * inv);
        o.w = pack2(a[14] * inv, a[15] * inv);
        *(uint4*)(aggp + base + 128) = o;
    }
}

// ---------- fused MFMA GEMM: h = relu(agg@W1l + x@W1r + b1) [LDS only];
// ----------   hW = bf16(h@W2l); outp = fp32(h@W2r + b2) ----------
// ALL global operands MFMA-fragment-packed (lane-contiguous 1 KB tiles — the
// L1 line-throughput fix that broke the ~50 us wall in R15).
#define PAD1 136
__global__ __launch_bounds__(256) void k_gemm12(
    const ushort* __restrict__ aggp, const ushort* __restrict__ xbp,
    const ushort* __restrict__ T1l, const ushort* __restrict__ T1r,
    const ushort* __restrict__ T2l, const ushort* __restrict__ T2r,
    const float* __restrict__ b1, const float* __restrict__ b2,
    ushort* __restrict__ hW, float* __restrict__ outp) {
    __shared__ ushort hS[2][16 * PAD1];
    const int lane = threadIdx.x & 63;
    const int wave = threadIdx.x >> 6;
    const int s = wave >> 1;              // row strip
    const int ch = wave & 1;              // col half
    const int quad = lane >> 4, r16 = lane & 15;
    const int row0 = blockIdx.x * 32 + s * 16;
    const int g = blockIdx.x * 2 + s;     // 16-row group index
    ushort* myS = &hS[s][0];

    // stage 1: 16x64 h-piece. All loads lane-contiguous packed tiles.
    f32x4 acc[4];
    #pragma unroll
    for (int nt = 0; nt < 4; nt++) acc[nt] = (f32x4){0.f, 0.f, 0.f, 0.f};
    #pragma unroll
    for (int kt = 0; kt < 4; kt++) {
        bf16x8 aAgg = load8(aggp + (size_t)(g * 4 + kt) * 512 + lane * 8);
        bf16x8 aXb  = load8(xbp  + (size_t)(g * 4 + kt) * 512 + lane * 8);
        #pragma unroll
        for (int nt = 0; nt < 4; nt++) {
            const int tile = ((ch * 4 + nt) * 4 + kt) * 512 + lane * 8;
            acc[nt] = __builtin_amdgcn_mfma_f32_16x16x32_bf16(aAgg, load8(T1l + tile), acc[nt], 0, 0, 0);
            acc[nt] = __builtin_amdgcn_mfma_f32_16x16x32_bf16(aXb,  load8(T1r + tile), acc[nt], 0, 0, 0);
        }
    }
    #pragma unroll
    for (int nt = 0; nt < 4; nt++) {
        int cc = ch * 64 + nt * 16 + r16;
        float bv = b1[cc];
        #pragma unroll
        for (int i = 0; i < 4; i++)
            myS[(quad * 4 + i) * PAD1 + cc] = f2bf(fmaxf(acc[nt][i] + bv, 0.f));
    }
    __syncthreads();

    // stage 2+3: hW piece (h@T2l) and outp piece (h@T2r), 16x32 each
    f32x4 acc2[2], acc3[2];
    #pragma unroll
    for (int nt = 0; nt < 2; nt++) {
        acc2[nt] = (f32x4){0.f, 0.f, 0.f, 0.f};
        acc3[nt] = (f32x4){0.f, 0.f, 0.f, 0.f};
    }
    #pragma unroll
    for (int kt = 0; kt < 4; kt++) {
        bf16x8 ah = load8(&myS[r16 * PAD1 + kt * 32 + quad * 8]);
        #pragma unroll
        for (int nt = 0; nt < 2; nt++) {
            const int tile = ((ch * 2 + nt) * 4 + kt) * 512 + lane * 8;
            acc2[nt] = __builtin_amdgcn_mfma_f32_16x16x32_bf16(ah, load8(T2l + tile), acc2[nt], 0, 0, 0);
            acc3[nt] = __builtin_amdgcn_mfma_f32_16x16x32_bf16(ah, load8(T2r + tile), acc3[nt], 0, 0, 0);
        }
    }
    #pragma unroll
    for (int nt = 0; nt < 2; nt++) {
        int cc = ch * 32 + nt * 16 + r16;
        float bv = b2[cc];
        #pragma unroll
        for (int i = 0; i < 4; i++) {
            int rr = row0 + quad * 4 + i;
            if (rr < NN) {
                hW[(size_t)rr * 64 + cc] = f2bf(acc2[nt][i]);
                outp[(size_t)rr * 64 + cc] = acc3[nt][i] + bv;
            }
        }
    }
}

// ---------- final: out = mean-gather(hW bf16, 128 B rows) + outp(fp32) ----------
// 8 lanes x 16B cover one row; lane c owns dims c*8..c*8+7. 4 gathers in flight.
__global__ void k_agg64f(const ushort* __restrict__ hW, const ushort* __restrict__ col,
                         const int* __restrict__ deg, const float* __restrict__ outp,
                         float* __restrict__ out) {
    int node = (blockIdx.x * blockDim.x + threadIdx.x) >> 6;
    int lane = threadIdx.x & 63;
    int q = lane >> 3;         // neighbor slot within group of 8
    int c = lane & 7;          // dim group: dims c*8 .. c*8+7
    int d = deg[node];
    int dd = min(d, BSTRIDE);
    const ushort* cb = col + (size_t)node * BSTRIDE;
    float a0=0.f,a1=0.f,a2=0.f,a3=0.f,a4=0.f,a5=0.f,a6=0.f,a7=0.f;
    for (int j0 = 0; j0 < dd; j0 += 64) {
        int idx = (j0 + lane < dd) ? (int)cb[j0 + lane] : 0;
        int cnt = min(64, dd - j0);
        int t = 0;
        for (; t + 32 <= cnt; t += 32) {     // 32 neighbors, 4 loads in flight
            int s0 = __shfl(idx, t + q);
            int s1 = __shfl(idx, t + 8 + q);
            int s2 = __shfl(idx, t + 16 + q);
            int s3 = __shfl(idx, t + 24 + q);
            uint4 u0 = *(const uint4*)(hW + (size_t)s0 * 64 + c * 8);
            uint4 u1 = *(const uint4*)(hW + (size_t)s1 * 64 + c * 8);
            uint4 u2 = *(const uint4*)(hW + (size_t)s2 * 64 + c * 8);
            uint4 u3 = *(const uint4*)(hW + (size_t)s3 * 64 + c * 8);
            ACC8(u0); ACC8(u1); ACC8(u2); ACC8(u3);
        }
        for (; t + 16 <= cnt; t += 16) {
            int s0 = __shfl(idx, t + q);
            int s1 = __shfl(idx, t + 8 + q);
            uint4 u0 = *(const uint4*)(hW + (size_t)s0 * 64 + c * 8);
            uint4 u1 = *(const uint4*)(hW + (size_t)s1 * 64 + c * 8);
            ACC8(u0); ACC8(u1);
        }
        for (; t < cnt; t += 8) {
            int s = __shfl(idx, t + q);
            if (t + q < cnt) {
                uint4 u = *(const uint4*)(hW + (size_t)s * 64 + c * 8);
                ACC8(u);
            }
        }
    }
    #pragma unroll
    for (int m = 8; m < 64; m <<= 1) {
        a0 += __shfl_xor(a0, m); a1 += __shfl_xor(a1, m);
        a2 += __shfl_xor(a2, m); a3 += __shfl_xor(a3, m);
        a4 += __shfl_xor(a4, m); a5 += __shfl_xor(a5, m);
        a6 += __shfl_xor(a6, m); a7 += __shfl_xor(a7, m);
    }
    if (q == 0) {
        float inv = 1.f / fmaxf((float)d, 1.f);
        float4 p0 = *(const float4*)(outp + (size_t)node * 64 + c * 8);
        float4 p1 = *(const float4*)(outp + (size_t)node * 64 + c * 8 + 4);
        float4 o;
        o.x = a0 * inv + p0.x; o.y = a1 * inv + p0.y;
        o.z = a2 * inv + p0.z; o.w = a3 * inv + p0.w;
        *(float4*)(out + (size_t)node * 64 + c * 8) = o;
        o.x = a4 * inv + p1.x; o.y = a5 * inv + p1.y;
        o.z = a6 * inv + p1.z; o.w = a7 * inv + p1.w;
        *(float4*)(out + (size_t)node * 64 + c * 8 + 4) = o;
    }
}

// ---------- launch ----------
extern "C" void kernel_launch(void* const* d_in, const int* in_sizes, int n_in,
                              void* d_out, int out_size, void* d_ws, size_t ws_size,
                              hipStream_t stream) {
    const float* x   = (const float*)d_in[0];
    const int*   ei  = (const int*)d_in[1];
    const float* W1l = (const float*)d_in[2];
    const float* W1r = (const float*)d_in[3];
    const float* b1  = (const float*)d_in[4];
    const float* W2l = (const float*)d_in[5];
    const float* W2r = (const float*)d_in[6];
    const float* b2  = (const float*)d_in[7];
    float* out = (float*)d_out;

    const int* src = ei;
    const int* dst = ei + NE;

    char* w = (char*)d_ws;
    ushort* col   = (ushort*)w;                  w += (size_t)NN * BSTRIDE * 2;      // 9.6 MB
    int* deg      = (int*)w;                     w += (size_t)50048 * 4;             // 0.2 MB
    ushort* cnt   = (ushort*)w;                  w += (size_t)P1_BLKS * C_BKT * 2;   // 0.2 MB
    ushort* xbp   = (ushort*)w;                  w += (size_t)RGRP * 2048 * 2;       // 12.8 MB packed
    ushort* T1l   = (ushort*)w;                  w += 128 * 128 * 2;                 // 32 KB packed
    ushort* T1r   = (ushort*)w;                  w += 128 * 128 * 2;                 // 32 KB packed
    ushort* T2l   = (ushort*)w;                  w += 64 * 128 * 2;                  // 16 KB packed
    ushort* T2r   = (ushort*)w;                  w += 64 * 128 * 2;                  // 16 KB packed
    ushort* aggp  = (ushort*)w;                  w += (size_t)RGRP * 2048 * 2;       // 12.8 MB packed
    ushort* hW    = (ushort*)w;                  w += (size_t)NN * 64 * 2;           // 6.4 MB bf16
    float* outp   = (float*)w;                   w += (size_t)NN * 64 * 4;           // 12.8 MB fp32
    uchar* xf8    = (uchar*)w;                   w += (size_t)NN * 128;              // 6.4 MB
    // cells (22.5 MB) aliases aggp+hW+outp (32 MB): consumed by k_part2 before
    // any of those is written; xf8/xbp are live alongside cells -> NOT aliased.
    uint* cells  = (uint*)aggp;

    k_pp<<<PP_PREP + P1_BLKS, 1024, 0, stream>>>(
        (const float4*)x, xbp, (uint*)xf8, W1l, W1r, W2l, W2r,
        T1l, T1r, T2l, T2r, src, dst, cells, cnt);
    k_part2<<<C_BKT, 1024, 0, stream>>>(cells, cnt, col, deg);

    k_agg128<<<NN / 4, 256, 0, stream>>>(xf8, col, deg, aggp);
    k_gemm12<<<(NN + 31) / 32, 256, 0, stream>>>(aggp, xbp, T1l, T1r, T2l, T2r, b1, b2, hW, outp);

    k_agg64f<<<NN / 4, 256, 0, stream>>>(hW, col, deg, outp, out);
}

// Round 19
// 197.144 us; speedup vs baseline: 1.0541x; 1.0541x over previous
//
#include <hip/hip_runtime.h>

#define NN 50000
#define NE 1600000
#define BSTRIDE 96   // max degree slots; Poisson(32) tail at 96 is ~e^-41 per node
#define C_BKT 196    // dst buckets of 256 nodes: ceil(50000/256)
#define P1_BLKS 512
#define P1_CHUNK 3125 // NE / P1_BLKS exactly
#define CAP 56       // per-(block,bucket) cell capacity; Poisson(16) P(>=56) ~ 1e-14
#define XCVT_BLKS 1563   // ceil(1600000 float4 / 1024)
#define WCVT_BLKS 48     // 49152 / 1024 exactly
#define PP_PREP (XCVT_BLKS + WCVT_BLKS)
#define RGRP 3128    // padded 16-row groups (50048 rows) for packed A arrays

typedef __bf16 bf16x8 __attribute__((ext_vector_type(8)));
typedef float  f32x4  __attribute__((ext_vector_type(4)));
typedef float  f32x2  __attribute__((ext_vector_type(2)));

// ---------- bf16 helpers (RNE) ----------
__device__ __forceinline__ float bfLo(uint u) { union { uint i; float f; } v; v.i = u << 16; return v.f; }
__device__ __forceinline__ float bfHi(uint u) { union { uint i; float f; } v; v.i = u & 0xffff0000u; return v.f; }
__device__ __forceinline__ ushort f2bf(float f) {
    union { float f; uint i; } v; v.f = f;
    uint r = v.i + 0x7fffu + ((v.i >> 16) & 1u);
    return (ushort)(r >> 16);
}
__device__ __forceinline__ uint pack2(float a, float b) {
    return (uint)f2bf(a) | ((uint)f2bf(b) << 16);
}
__device__ __forceinline__ bf16x8 load8(const ushort* p) {
    union { uint4 u; bf16x8 b; } v; v.u = *(const uint4*)p; return v.b;
}

#define ACC8(u) { a0 += bfLo(u.x); a1 += bfHi(u.x); a2 += bfLo(u.y); a3 += bfHi(u.y); \
                  a4 += bfLo(u.z); a5 += bfHi(u.z); a6 += bfLo(u.w); a7 += bfHi(u.w); }

// fp8 x4 (one uint) -> 4 fp32 accumulated at offset o
#define CVA(u, o) { f32x2 p0 = __builtin_amdgcn_cvt_pk_f32_fp8((int)(u), 0); \
                    f32x2 p1 = __builtin_amdgcn_cvt_pk_f32_fp8((int)(u), 1); \
                    a[(o)+0] += p0.x; a[(o)+1] += p0.y; a[(o)+2] += p1.x; a[(o)+3] += p1.y; }
#define ACCF8(v) { CVA((v).x, 0); CVA((v).y, 4); CVA((v).z, 8); CVA((v).w, 12); }

// MFMA-fragment-packed offset (ushort units) for element (row/col n, depth k):
// tile = (n>>4)*4 + (k>>5); within-tile: quad=(k>>3)&3, m=n&15, j=k&7
// off = tile*512 + quad*128 + m*8 + j  -> one wave tile = contiguous 1 KB.
__device__ __forceinline__ int pkOff(int n, int k) {
    return (((n >> 4) * 4 + (k >> 5)) * 512) + (((k >> 3) & 3) * 128) + ((n & 15) * 8) + (k & 7);
}

// ---------- fused prep (x->packed bf16 + x->fp8, weights->packed bf16) + radix pass 1 ----------
__global__ __launch_bounds__(1024) void k_pp(
    const float4* __restrict__ x, ushort* __restrict__ xbp, uint* __restrict__ xf8,
    const float* __restrict__ W1l, const float* __restrict__ W1r,
    const float* __restrict__ W2l, const float* __restrict__ W2r,
    ushort* __restrict__ T1l, ushort* __restrict__ T1r,
    ushort* __restrict__ T2l, ushort* __restrict__ T2r,
    const int* __restrict__ src, const int* __restrict__ dst,
    uint* __restrict__ cells, ushort* __restrict__ cnt) {
    __shared__ uint hist[C_BKT];
    const int b = blockIdx.x;
    const int tid = threadIdx.x;
    if (b < XCVT_BLKS) {
        int i = b * 1024 + tid;                   // 1.6M float4 total
        if (i < NN * 128 / 4) {
            float4 v = x[i];
            int r = i >> 5, k0 = (i & 31) * 4;    // row, depth base (4 consecutive k)
            ushort4 o; o.x = f2bf(v.x); o.y = f2bf(v.y); o.z = f2bf(v.z); o.w = f2bf(v.w);
            *(ushort4*)(xbp + pkOff(r, k0)) = o;  // packed write (8-B aligned)
            uint rr = (uint)__builtin_amdgcn_cvt_pk_fp8_f32(v.x, v.y, 0, 0);
            rr = (uint)__builtin_amdgcn_cvt_pk_fp8_f32(v.z, v.w, (int)rr, 1);
            xf8[i] = rr;                          // 4 fp8 = dims 4i..4i+3, row-major
        }
    } else if (b < PP_PREP) {
        int i = (b - XCVT_BLKS) * 1024 + tid;     // 0 .. 49151
        if (i < 16384) {
            int k = i >> 7, n = i & 127; T1l[pkOff(n, k)] = f2bf(W1l[i]);
        } else if (i < 32768) {
            int j = i - 16384; int k = j >> 7, n = j & 127; T1r[pkOff(n, k)] = f2bf(W1r[j]);
        } else if (i < 40960) {
            int j = i - 32768; int k = j >> 6, n = j & 63;  T2l[pkOff(n, k)] = f2bf(W2l[j]);
        } else {
            int j = i - 40960; int k = j >> 6, n = j & 63;  T2r[pkOff(n, k)] = f2bf(W2r[j]);
        }
    } else {
        // radix pass 1: partition edges into block-private (bucket) cells, LDS atomics only
        const int b2 = b - PP_PREP;               // 0..511
        for (int i = tid; i < C_BKT; i += 1024) hist[i] = 0;
        __syncthreads();
        const int beg = b2 * P1_CHUNK;
        uint* myCells = cells + (size_t)b2 * C_BKT * CAP;
        for (int i = beg + tid; i < beg + P1_CHUNK; i += 1024) {
            int d = dst[i];
            int s = src[i];
            int c = d >> 8;
            uint p = atomicAdd(&hist[c], 1);
            if (p < CAP) myCells[c * CAP + p] = ((uint)(d & 255) << 16) | (uint)s;
        }
        __syncthreads();
        for (int i = tid; i < C_BKT; i += 1024)
            cnt[(size_t)b2 * C_BKT + i] = (ushort)min(hist[i], (uint)CAP);
    }
}

// ---------- radix pass 2: per-bucket gather, final col slots via LDS atomics ----------
__global__ __launch_bounds__(1024) void k_part2(const uint* __restrict__ cells,
                        const ushort* __restrict__ cnt,
                        ushort* __restrict__ col, int* __restrict__ deg) {
    __shared__ uint hist[256];
    const int c = blockIdx.x;
    if (threadIdx.x < 256) hist[threadIdx.x] = 0;
    __syncthreads();
    const int b = threadIdx.x >> 1;            // 0..511
    const int sub = threadIdx.x & 1;
    const uint* cell = cells + ((size_t)b * C_BKT + c) * CAP;
    const int n = cnt[(size_t)b * C_BKT + c];
    const int nodeBase = c << 8;
    for (int j = sub; j < n; j += 2) {
        uint e = cell[j];
        int dl = e >> 16;
        uint p = atomicAdd(&hist[dl], 1);
        if (p < BSTRIDE)
            col[(size_t)(nodeBase + dl) * BSTRIDE + p] = (ushort)(e & 0xFFFF);
    }
    __syncthreads();
    if (threadIdx.x < 256) {
        int node = nodeBase + threadIdx.x;
        if (node < NN) deg[node] = (int)hist[threadIdx.x];
    }
}

// ---------- aggregation, 128-dim fp8 rows -> PACKED bf16 agg1 ----------
// one wave per node; 8 lanes x 16B cover one 128B row -> 8 neighbors/wave-load;
// 2 loads in flight (4-deep unroll regressed: VGPR 52, occupancy 34% — R17).
__global__ void k_agg128(const uchar* __restrict__ xf8, const ushort* __restrict__ col,
                         const int* __restrict__ deg, ushort* __restrict__ aggp) {
    int node = (blockIdx.x * blockDim.x + threadIdx.x) >> 6;
    int lane = threadIdx.x & 63;
    int q = lane >> 3;         // neighbor slot within group of 8
    int c = lane & 7;          // dim group: dims c*16 .. c*16+15
    int d = deg[node];
    int dd = min(d, BSTRIDE);
    const ushort* cb = col + (size_t)node * BSTRIDE;
    float a[16];
    #pragma unroll
    for (int i = 0; i < 16; i++) a[i] = 0.f;
    for (int j0 = 0; j0 < dd; j0 += 64) {
        int idx = (j0 + lane < dd) ? (int)cb[j0 + lane] : 0;
        int cnt = min(64, dd - j0);
        int t = 0;
        for (; t + 16 <= cnt; t += 16) {     // 16 neighbors, 2 loads in flight
            int s0 = __shfl(idx, t + q);
            int s1 = __shfl(idx, t + 8 + q);
            uint4 u0 = *(const uint4*)(xf8 + (size_t)s0 * 128 + c * 16);
            uint4 u1 = *(const uint4*)(xf8 + (size_t)s1 * 128 + c * 16);
            ACCF8(u0); ACCF8(u1);
        }
        for (; t < cnt; t += 8) {
            int s = __shfl(idx, t + q);
            if (t + q < cnt) {
                uint4 u = *(const uint4*)(xf8 + (size_t)s * 128 + c * 16);
                ACCF8(u);
            }
        }
    }
    #pragma unroll
    for (int m = 8; m < 64; m <<= 1) {
        #pragma unroll
        for (int i = 0; i < 16; i++) a[i] += __shfl_xor(a[i], m);
    }
    if (q == 0) {
        float inv = 1.f / fmaxf((float)d, 1.f);
        // packed write: dims c*16..+7 -> (kt=c>>1, quad=(c&1)*2), dims +8..+15 -> quad+1
        int base = ((node >> 4) * 4 + (c >> 1)) * 512 + ((c & 1) * 2) * 128 + (node & 15) * 8;
        uint4 o;
        o.x = pack2(a[0] * inv, a[1] * inv);
        o.y = pack2(a[2] * inv, a[3] * inv);
        o.z = pack2(a[4] * inv, a[5] * inv);
        o.w = pack2(a[6] * inv, a[7] * inv);
        *(uint4*)(aggp + base) = o;
        o.x = pack2(a[8] * inv, a[9] * inv);
        o.y = pack2(a[10] * inv, a[11] * inv);
        o.z = pack2(a[12] * inv, a[13] * inv);
        o.w = pack2(a[14] * inv, a[15] * inv);
        *(uint4*)(aggp + base + 128) = o;
    }
}

// ---------- fused MFMA GEMM: h = relu(agg@W1l + x@W1r + b1) [LDS only];
// ----------   hW = bf16(h@W2l); outp = fp32(h@W2r + b2) ----------
// ALL global operands MFMA-fragment-packed (lane-contiguous 1 KB tiles — the
// L1 line-throughput fix that broke the ~50 us wall in R15).
#define PAD1 136
__global__ __launch_bounds__(256) void k_gemm12(
    const ushort* __restrict__ aggp, const ushort* __restrict__ xbp,
    const ushort* __restrict__ T1l, const ushort* __restrict__ T1r,
    const ushort* __restrict__ T2l, const ushort* __restrict__ T2r,
    const float* __restrict__ b1, const float* __restrict__ b2,
    ushort* __restrict__ hW, float* __restrict__ outp) {
    __shared__ ushort hS[2][16 * PAD1];
    const int lane = threadIdx.x & 63;
    const int wave = threadIdx.x >> 6;
    const int s = wave >> 1;              // row strip
    const int ch = wave & 1;              // col half
    const int quad = lane >> 4, r16 = lane & 15;
    const int row0 = blockIdx.x * 32 + s * 16;
    const int g = blockIdx.x * 2 + s;     // 16-row group index
    ushort* myS = &hS[s][0];

    // stage 1: 16x64 h-piece. All loads lane-contiguous packed tiles.
    f32x4 acc[4];
    #pragma unroll
    for (int nt = 0; nt < 4; nt++) acc[nt] = (f32x4){0.f, 0.f, 0.f, 0.f};
    #pragma unroll
    for (int kt = 0; kt < 4; kt++) {
        bf16x8 aAgg = load8(aggp + (size_t)(g * 4 + kt) * 512 + lane * 8);
        bf16x8 aXb  = load8(xbp  + (size_t)(g * 4 + kt) * 512 + lane * 8);
        #pragma unroll
        for (int nt = 0; nt < 4; nt++) {
            const int tile = ((ch * 4 + nt) * 4 + kt) * 512 + lane * 8;
            acc[nt] = __builtin_amdgcn_mfma_f32_16x16x32_bf16(aAgg, load8(T1l + tile), acc[nt], 0, 0, 0);
            acc[nt] = __builtin_amdgcn_mfma_f32_16x16x32_bf16(aXb,  load8(T1r + tile), acc[nt], 0, 0, 0);
        }
    }
    #pragma unroll
    for (int nt = 0; nt < 4; nt++) {
        int cc = ch * 64 + nt * 16 + r16;
        float bv = b1[cc];
        #pragma unroll
        for (int i = 0; i < 4; i++)
            myS[(quad * 4 + i) * PAD1 + cc] = f2bf(fmaxf(acc[nt][i] + bv, 0.f));
    }
    __syncthreads();

    // stage 2+3: hW piece (h@T2l) and outp piece (h@T2r), 16x32 each
    f32x4 acc2[2], acc3[2];
    #pragma unroll
    for (int nt = 0; nt < 2; nt++) {
        acc2[nt] = (f32x4){0.f, 0.f, 0.f, 0.f};
        acc3[nt] = (f32x4){0.f, 0.f, 0.f, 0.f};
    }
    #pragma unroll
    for (int kt = 0; kt < 4; kt++) {
        bf16x8 ah = load8(&myS[r16 * PAD1 + kt * 32 + quad * 8]);
        #pragma unroll
        for (int nt = 0; nt < 2; nt++) {
            const int tile = ((ch * 2 + nt) * 4 + kt) * 512 + lane * 8;
            acc2[nt] = __builtin_amdgcn_mfma_f32_16x16x32_bf16(ah, load8(T2l + tile), acc2[nt], 0, 0, 0);
            acc3[nt] = __builtin_amdgcn_mfma_f32_16x16x32_bf16(ah, load8(T2r + tile), acc3[nt], 0, 0, 0);
        }
    }
    #pragma unroll
    for (int nt = 0; nt < 2; nt++) {
        int cc = ch * 32 + nt * 16 + r16;
        float bv = b2[cc];
        #pragma unroll
        for (int i = 0; i < 4; i++) {
            int rr = row0 + quad * 4 + i;
            if (rr < NN) {
                hW[(size_t)rr * 64 + cc] = f2bf(acc2[nt][i]);
                outp[(size_t)rr * 64 + cc] = acc3[nt][i] + bv;
            }
        }
    }
}

// ---------- final: out = mean-gather(hW bf16, 128 B rows) + outp(fp32) ----------
// 8 lanes x 16B cover one row; lane c owns dims c*8..c*8+7; 2 loads in flight.
__global__ void k_agg64f(const ushort* __restrict__ hW, const ushort* __restrict__ col,
                         const int* __restrict__ deg, const float* __restrict__ outp,
                         float* __restrict__ out) {
    int node = (blockIdx.x * blockDim.x + threadIdx.x) >> 6;
    int lane = threadIdx.x & 63;
    int q = lane >> 3;         // neighbor slot within group of 8
    int c = lane & 7;          // dim group: dims c*8 .. c*8+7
    int d = deg[node];
    int dd = min(d, BSTRIDE);
    const ushort* cb = col + (size_t)node * BSTRIDE;
    float a0=0.f,a1=0.f,a2=0.f,a3=0.f,a4=0.f,a5=0.f,a6=0.f,a7=0.f;
    for (int j0 = 0; j0 < dd; j0 += 64) {
        int idx = (j0 + lane < dd) ? (int)cb[j0 + lane] : 0;
        int cnt = min(64, dd - j0);
        int t = 0;
        for (; t + 16 <= cnt; t += 16) {
            int s0 = __shfl(idx, t + q);
            int s1 = __shfl(idx, t + 8 + q);
            uint4 u0 = *(const uint4*)(hW + (size_t)s0 * 64 + c * 8);
            uint4 u1 = *(const uint4*)(hW + (size_t)s1 * 64 + c * 8);
            ACC8(u0); ACC8(u1);
        }
        for (; t < cnt; t += 8) {
            int s = __shfl(idx, t + q);
            if (t + q < cnt) {
                uint4 u = *(const uint4*)(hW + (size_t)s * 64 + c * 8);
                ACC8(u);
            }
        }
    }
    #pragma unroll
    for (int m = 8; m < 64; m <<= 1) {
        a0 += __shfl_xor(a0, m); a1 += __shfl_xor(a1, m);
        a2 += __shfl_xor(a2, m); a3 += __shfl_xor(a3, m);
        a4 += __shfl_xor(a4, m); a5 += __shfl_xor(a5, m);
        a6 += __shfl_xor(a6, m); a7 += __shfl_xor(a7, m);
    }
    if (q == 0) {
        float inv = 1.f / fmaxf((float)d, 1.f);
        float4 p0 = *(const float4*)(outp + (size_t)node * 64 + c * 8);
        float4 p1 = *(const float4*)(outp + (size_t)node * 64 + c * 8 + 4);
        float4 o;
        o.x = a0 * inv + p0.x; o.y = a1 * inv + p0.y;
        o.z = a2 * inv + p0.z; o.w = a3 * inv + p0.w;
        *(float4*)(out + (size_t)node * 64 + c * 8) = o;
        o.x = a4 * inv + p1.x; o.y = a5 * inv + p1.y;
        o.z = a6 * inv + p1.z; o.w = a7 * inv + p1.w;
        *(float4*)(out + (size_t)node * 64 + c * 8 + 4) = o;
    }
}

// ---------- launch ----------
extern "C" void kernel_launch(void* const* d_in, const int* in_sizes, int n_in,
                              void* d_out, int out_size, void* d_ws, size_t ws_size,
                              hipStream_t stream) {
    const float* x   = (const float*)d_in[0];
    const int*   ei  = (const int*)d_in[1];
    const float* W1l = (const float*)d_in[2];
    const float* W1r = (const float*)d_in[3];
    const float* b1  = (const float*)d_in[4];
    const float* W2l = (const float*)d_in[5];
    const float* W2r = (const float*)d_in[6];
    const float* b2  = (const float*)d_in[7];
    float* out = (float*)d_out;

    const int* src = ei;
    const int* dst = ei + NE;

    char* w = (char*)d_ws;
    ushort* col   = (ushort*)w;                  w += (size_t)NN * BSTRIDE * 2;      // 9.6 MB
    int* deg      = (int*)w;                     w += (size_t)50048 * 4;             // 0.2 MB
    ushort* cnt   = (ushort*)w;                  w += (size_t)P1_BLKS * C_BKT * 2;   // 0.2 MB
    ushort* xbp   = (ushort*)w;                  w += (size_t)RGRP * 2048 * 2;       // 12.8 MB packed
    ushort* T1l   = (ushort*)w;                  w += 128 * 128 * 2;                 // 32 KB packed
    ushort* T1r   = (ushort*)w;                  w += 128 * 128 * 2;                 // 32 KB packed
    ushort* T2l   = (ushort*)w;                  w += 64 * 128 * 2;                  // 16 KB packed
    ushort* T2r   = (ushort*)w;                  w += 64 * 128 * 2;                  // 16 KB packed
    ushort* aggp  = (ushort*)w;                  w += (size_t)RGRP * 2048 * 2;       // 12.8 MB packed
    ushort* hW    = (ushort*)w;                  w += (size_t)NN * 64 * 2;           // 6.4 MB bf16
    float* outp   = (float*)w;                   w += (size_t)NN * 64 * 4;           // 12.8 MB fp32
    uchar* xf8    = (uchar*)w;                   w += (size_t)NN * 128;              // 6.4 MB
    // cells (22.5 MB) aliases aggp+hW+outp (32 MB): consumed by k_part2 before
    // any of those is written; xf8/xbp are live alongside cells -> NOT aliased.
    uint* cells  = (uint*)aggp;

    k_pp<<<PP_PREP + P1_BLKS, 1024, 0, stream>>>(
        (const float4*)x, xbp, (uint*)xf8, W1l, W1r, W2l, W2r,
        T1l, T1r, T2l, T2r, src, dst, cells, cnt);
    k_part2<<<C_BKT, 1024, 0, stream>>>(cells, cnt, col, deg);

    k_agg128<<<NN / 4, 256, 0, stream>>>(xf8, col, deg, aggp);
    k_gemm12<<<(NN + 31) / 32, 256, 0, stream>>>(aggp, xbp, T1l, T1r, T2l, T2r, b1, b2, hW, outp);

    k_agg64f<<<NN / 4, 256, 0, stream>>>(hW, col, deg, outp, out);
}